// Round 6
// baseline (88.047 us; speedup 1.0000x reference)
//
#include <hip/hip_runtime.h>
#include <cmath>

#define HW (512*512)
#define NSUB 2048            // 64 bins x 32 sub-bins
#define THREADS1 1024
#define BLKS_PER_IMG 32
#define TBL (3 * NSUB + 1)   // +1 word skew: same index -> adjacent bank
#define NTAP 160             // +-2.5 bins = 5 sigma; truncation < 5e-6

__device__ __forceinline__ float fexp2(float x) { return __builtin_amdgcn_exp2f(x); }
__device__ __forceinline__ float flog2(float x) { return __builtin_amdgcn_logf(x); }

// Fused phase 1: RGB -> Lab -> integer sub-bin counting into dual lane-parity
// skewed LDS tables; per-block 160-tap conv to 64 bins via a precomputed
// weight table; emits 192-float partial histogram (conv is linear over blocks).
// NEW r6: pixel pass is a 4-group software pipeline -- group g+1's three
// float2 loads issue BEFORE group g's compute, so the CU's HBM/LLC stream
// overlaps compute instead of serializing ahead of it. Groups re-strided
// (g*2048 + t*2) so every load stays 8B/lane coalesced. Per-pixel math and
// integer counts unchanged -> output bit-identical to r5.
__global__ __launch_bounds__(THREADS1) void count_conv_kernel(const float* __restrict__ img,
                                                              float* __restrict__ part) {
    __align__(16) __shared__ unsigned sh[2 * TBL + 2];   // ~48 KB; reused as float subf
    __shared__ float W[NTAP];
    __shared__ float hb[3][64];
    const int tid = threadIdx.x;
    {   // vectorized zero-init (ds_write_b128)
        uint4* z = reinterpret_cast<uint4*>(sh);
        const uint4 zero = {0u, 0u, 0u, 0u};
        for (int i = tid; i < (2 * TBL + 2) / 4; i += THREADS1) z[i] = zero;
    }
    if (tid < NTAP) {        // weight table: W[t], offset o = t-64 from bin base
        const float C = 2.8853901f;          // 2/ln2
        float d = ((float)tid - 63.5f) * (1.0f / 32.0f) - 0.5f;
        W[tid] = fexp2(-C * d * d);
    }
    __syncthreads();

    unsigned* h = sh + (tid & 1) * TBL;    // lane parity selects skewed table

    const int b  = blockIdx.y;
    const int bx = blockIdx.x;
    const float* base = img + (size_t)b * 3u * HW;

    // 8 px/thread as 4 groups of 2; group g covers px [bx*8192 + g*2048 + 2t]
    const int p0 = bx * (THREADS1 * 8) + tid * 2;   // group stride 2048 px

    float2 rc, gc, bc;       // current group
    float2 rn, gn, bn;       // next group (prefetch)
    rc = *reinterpret_cast<const float2*>(base + p0);
    gc = *reinterpret_cast<const float2*>(base + p0 + HW);
    bc = *reinterpret_cast<const float2*>(base + p0 + 2 * HW);

    #pragma unroll
    for (int g = 0; g < 4; ++g) {
        if (g < 3) {         // issue next group's loads before computing current
            const int pn = p0 + (g + 1) * (THREADS1 * 2);
            rn = *reinterpret_cast<const float2*>(base + pn);
            gn = *reinterpret_cast<const float2*>(base + pn + HW);
            bn = *reinterpret_cast<const float2*>(base + pn + 2 * HW);
        }
        float rr[2] = {rc.x, rc.y};
        float gg[2] = {gc.x, gc.y};
        float bl[2] = {bc.x, bc.y};

        #pragma unroll
        for (int k = 0; k < 2; ++k) {
            // sRGB -> linear (log2 inputs provably >= 0.09: no denormal risk)
            float lr = (rr[k] > 0.04045f) ? fexp2(2.4f * flog2((rr[k] + 0.055f) * (1.0f / 1.055f))) : rr[k] * (1.0f / 12.92f);
            float lg = (gg[k] > 0.04045f) ? fexp2(2.4f * flog2((gg[k] + 0.055f) * (1.0f / 1.055f))) : gg[k] * (1.0f / 12.92f);
            float lb = (bl[k] > 0.04045f) ? fexp2(2.4f * flog2((bl[k] + 0.055f) * (1.0f / 1.055f))) : bl[k] * (1.0f / 12.92f);

            // XYZ with xn/zn folded into the matrix rows
            float x = 0.4339530f * lr + 0.3762197f * lg + 0.1898288f * lb; // x/0.950456
            float y = 0.2126710f * lr + 0.7151600f * lg + 0.0721690f * lb;
            float z = 0.0177578f * lr + 0.1094766f * lg + 0.8727661f * lb; // z/1.088754

            float fx = (x > 0.008856f) ? fexp2(flog2(x) * (1.0f/3.0f)) : 7.787f * x + 16.0f/116.0f;
            float fy = (y > 0.008856f) ? fexp2(flog2(y) * (1.0f/3.0f)) : 7.787f * y + 16.0f/116.0f;
            float fz = (z > 0.008856f) ? fexp2(flog2(z) * (1.0f/3.0f)) : 7.787f * z + 16.0f/116.0f;

            // sub-bin indices (scale/offset folded); ranges provably in [0,2048)
            int iL = (int)(2375.68f    * fy - 327.68f);
            int iA = (int)(4015.6863f  * (fx - fy) + 1028.01569f);
            int iB = (int)(1606.27451f * (fy - fz) + 1028.01569f);

            atomicAdd(&h[iL], 1u);
            atomicAdd(&h[NSUB + iA], 1u);
            atomicAdd(&h[2 * NSUB + iB], 1u);
        }
        rc = rn; gc = gn; bc = bn;   // rotate pipeline (fully unrolled: static)
    }
    __syncthreads();

    // merge dual tables in place as float over table-0 storage (index i's
    // read+write stay in one thread; table-1 slots are never overwritten)
    float* subf = reinterpret_cast<float*>(sh);
    for (int i = tid; i < 3 * NSUB; i += THREADS1) {
        unsigned s = sh[i] + sh[TBL + i];          // <= 16384: exact in f32
        subf[i] = (float)s;
    }
    __syncthreads();

    // per-block conv via weight table: s = 32j - 64 + t, t = q + 16i
    // W[] reads: same-address broadcast (free); subf[] reads: 2 lanes/bank (free)
    const int j = tid >> 4;                // bin 0..63
    const int q = tid & 15;                // 16 lanes per bin
    const int s_lo = 32 * j - 64;
    #pragma unroll
    for (int ch = 0; ch < 3; ++ch) {
        float acc = 0.0f;
        #pragma unroll
        for (int i = 0; i < 10; ++i) {
            int t = q + 16 * i;
            int s = s_lo + t;
            if ((unsigned)s < (unsigned)NSUB)
                acc += subf[ch * NSUB + s] * W[t];
        }
        acc += __shfl_xor(acc, 1, 64);
        acc += __shfl_xor(acc, 2, 64);
        acc += __shfl_xor(acc, 4, 64);
        acc += __shfl_xor(acc, 8, 64);
        if (q == 0) hb[ch][j] = acc;
    }
    __syncthreads();

    if (tid < 192) {                       // hb flat layout == output layout
        float* dst = part + (size_t)(b * BLKS_PER_IMG + bx) * 192;
        dst[tid] = (&hb[0][0])[tid];
    }
}

// Phase 2 (tiny): sum 32 partial 192-bin histograms per image, normalize per
// channel via wave reduction (wave == channel), write out. ~393 KB total read.
__global__ __launch_bounds__(192) void finalize_kernel(const float* __restrict__ part,
                                                       float* __restrict__ out) {
    const int b = blockIdx.x;
    const int t = threadIdx.x;             // 0..191; wave (t>>6) == channel
    const float* p0 = part + (size_t)b * BLKS_PER_IMG * 192 + t;
    float v = 0.0f;
    #pragma unroll
    for (int k = 0; k < BLKS_PER_IMG; ++k) v += p0[k * 192];
    float s = v;                           // per-channel sum across the wave's 64 bins
    #pragma unroll
    for (int off = 32; off >= 1; off >>= 1) s += __shfl_down(s, off, 64);
    s = __shfl(s, 0, 64);
    out[b * 192 + t] = v / (s + 1e-8f);
}

extern "C" void kernel_launch(void* const* d_in, const int* in_sizes, int n_in,
                              void* d_out, int out_size, void* d_ws, size_t ws_size,
                              hipStream_t stream) {
    const float* img = (const float*)d_in[0];
    float* out     = (float*)d_out;
    float* part    = (float*)d_ws;        // 16*32 partials * 192 f32 = 393 KB

    const int B = in_sizes[0] / (3 * HW); // 16

    count_conv_kernel<<<dim3(BLKS_PER_IMG, B), THREADS1, 0, stream>>>(img, part);
    finalize_kernel<<<B, 192, 0, stream>>>(part, out);
}

// Round 8
// 86.687 us; speedup vs baseline: 1.0157x; 1.0157x over previous
//
#include <hip/hip_runtime.h>
#include <cmath>

#define HW (512*512)
#define NSUB 2048            // 64 bins x 32 sub-bins
#define THREADS1 1024
#define BLKS_PER_IMG 32
#define PART_WORDS (3 * NSUB / 2)   // 3072 u32 per partial (u16-packed sub-bins)

__device__ __forceinline__ float fexp2(float x) { return __builtin_amdgcn_exp2f(x); }
__device__ __forceinline__ float flog2(float x) { return __builtin_amdgcn_logf(x); }

// Phase 1: RGB -> Lab -> integer sub-bin counting into dual wave-parity LDS
// tables (3 ds_add_u32 per pixel). Per-block partial tables written to ws as
// packed u16 pairs (plain coalesced u32 stores; max count/block = 8192 < 2^16).
// [r8: restored verbatim from r1 -- best measured passing variant, 87.19 us]
__global__ __launch_bounds__(THREADS1) void count_kernel(const float* __restrict__ img,
                                                         unsigned* __restrict__ part) {
    __shared__ unsigned sh[2][3 * NSUB];   // 48 KB
    const int tid = threadIdx.x;
    unsigned* flat = &sh[0][0];
    for (int i = tid; i < 2 * 3 * NSUB; i += THREADS1) flat[i] = 0u;
    __syncthreads();

    unsigned* h = sh[(tid >> 6) & 1];      // wave parity selects table

    const int b  = blockIdx.y;
    const int bx = blockIdx.x;
    const float* base = img + (size_t)b * 3u * HW;

    const int stride = BLKS_PER_IMG * THREADS1 * 4;
    for (int p = (bx * THREADS1 + tid) * 4; p < HW; p += stride) {
        float4 r4 = *reinterpret_cast<const float4*>(base + p);
        float4 g4 = *reinterpret_cast<const float4*>(base + p + HW);
        float4 b4 = *reinterpret_cast<const float4*>(base + p + 2 * HW);
        float rr[4] = {r4.x, r4.y, r4.z, r4.w};
        float gg[4] = {g4.x, g4.y, g4.z, g4.w};
        float bl[4] = {b4.x, b4.y, b4.z, b4.w};

        #pragma unroll
        for (int k = 0; k < 4; ++k) {
            // sRGB -> linear (log2 inputs provably >= 0.09: no denormal risk)
            float lr = (rr[k] > 0.04045f) ? fexp2(2.4f * flog2((rr[k] + 0.055f) * (1.0f / 1.055f))) : rr[k] * (1.0f / 12.92f);
            float lg = (gg[k] > 0.04045f) ? fexp2(2.4f * flog2((gg[k] + 0.055f) * (1.0f / 1.055f))) : gg[k] * (1.0f / 12.92f);
            float lb = (bl[k] > 0.04045f) ? fexp2(2.4f * flog2((bl[k] + 0.055f) * (1.0f / 1.055f))) : bl[k] * (1.0f / 12.92f);

            // XYZ with xn/zn folded into the matrix rows
            float x = 0.4339530f * lr + 0.3762197f * lg + 0.1898288f * lb; // x/0.950456
            float y = 0.2126710f * lr + 0.7151600f * lg + 0.0721690f * lb;
            float z = 0.0177578f * lr + 0.1094766f * lg + 0.8727661f * lb; // z/1.088754

            float fx = (x > 0.008856f) ? fexp2(flog2(x) * (1.0f/3.0f)) : 7.787f * x + 16.0f/116.0f;
            float fy = (y > 0.008856f) ? fexp2(flog2(y) * (1.0f/3.0f)) : 7.787f * y + 16.0f/116.0f;
            float fz = (z > 0.008856f) ? fexp2(flog2(z) * (1.0f/3.0f)) : 7.787f * z + 16.0f/116.0f;

            // sub-bin indices (scale/offset folded); ranges provably in [0,2048)
            int iL = (int)(2375.68f    * fy - 327.68f);
            int iA = (int)(4015.6863f  * (fx - fy) + 1028.01569f);
            int iB = (int)(1606.27451f * (fy - fz) + 1028.01569f);

            atomicAdd(&h[iL], 1u);
            atomicAdd(&h[NSUB + iA], 1u);
            atomicAdd(&h[2 * NSUB + iB], 1u);
        }
    }
    __syncthreads();

    // merge dual tables -> per-block partial, packed as u16 pairs
    unsigned* dst = part + (size_t)(b * BLKS_PER_IMG + bx) * PART_WORDS;
    for (int i = tid; i < PART_WORDS; i += THREADS1) {
        unsigned s0 = sh[0][2 * i]     + sh[1][2 * i];
        unsigned s1 = sh[0][2 * i + 1] + sh[1][2 * i + 1];
        dst[i] = s0 | (s1 << 16);
    }
}

// Phase 2: reduce 32 u16-packed partials (1024 threads: 1 packed word each),
// truncated Gaussian conv -> 64 bins (16 lanes/bin, 204-tap window), normalize.
__global__ __launch_bounds__(1024) void conv_norm_kernel(const unsigned* __restrict__ part,
                                                         float* __restrict__ out) {
    __shared__ float sub[NSUB];
    __shared__ float hb[64];
    const int img = blockIdx.x / 3;
    const int ch  = blockIdx.x % 3;
    const int t   = threadIdx.x;           // u32 word index 0..1023 within channel

    const unsigned* p0 = part + (size_t)img * BLKS_PER_IMG * PART_WORDS
                              + (size_t)ch * (NSUB / 2) + t;
    unsigned s0 = 0, s1 = 0;
    #pragma unroll
    for (int k = 0; k < BLKS_PER_IMG; ++k) {
        unsigned v = p0[(size_t)k * PART_WORDS];
        s0 += v & 0xFFFFu;
        s1 += v >> 16;
    }
    sub[2 * t]     = (float)s0;            // exact: integer sums < 2^24
    sub[2 * t + 1] = (float)s1;
    __syncthreads();

    // d(s,j) = (s+0.5)/32 - 0.5 - j; 204 taps: s in [32j-86, 32j+117]
    const int j = t >> 4;                  // bin 0..63
    const int q = t & 15;                  // 16 lanes per bin
    const float C = 2.8853901f;            // 2/ln2
    const float jf = (float)j + 0.5f - (0.5f / 32.0f);
    const int s_lo = 32 * j - 86;
    float acc = 0.0f;
    #pragma unroll
    for (int i = 0; i < 13; ++i) {
        int s = s_lo + q + 16 * i;
        if (q + 16 * i < 204 && (unsigned)s < (unsigned)NSUB) {
            float d = (float)s * (1.0f / 32.0f) - jf;
            acc += sub[s] * fexp2(-C * d * d);
        }
    }
    acc += __shfl_xor(acc, 1, 64);
    acc += __shfl_xor(acc, 2, 64);
    acc += __shfl_xor(acc, 4, 64);
    acc += __shfl_xor(acc, 8, 64);
    if (q == 0) hb[j] = acc;
    __syncthreads();

    if (t < 64) {
        float v = hb[t];
        float s = v;
        #pragma unroll
        for (int off = 32; off >= 1; off >>= 1) s += __shfl_down(s, off, 64);
        s = __shfl(s, 0, 64);
        out[img * 192 + ch * 64 + t] = v / (s + 1e-8f);
    }
}

extern "C" void kernel_launch(void* const* d_in, const int* in_sizes, int n_in,
                              void* d_out, int out_size, void* d_ws, size_t ws_size,
                              hipStream_t stream) {
    const float* img = (const float*)d_in[0];
    float* out     = (float*)d_out;
    unsigned* part = (unsigned*)d_ws;     // 16*32 partials * 3072 u32 = 6.3 MB

    const int B = in_sizes[0] / (3 * HW); // 16

    count_kernel<<<dim3(BLKS_PER_IMG, B), THREADS1, 0, stream>>>(img, part);
    conv_norm_kernel<<<B * 3, 1024, 0, stream>>>(part, out);
}